// Round 1
// baseline (506.508 us; speedup 1.0000x reference)
//
#include <hip/hip_runtime.h>
#include <hip/hip_bf16.h>
#include <stdint.h>

typedef __attribute__((ext_vector_type(8))) short bf16x8;
typedef __attribute__((ext_vector_type(4))) float f32x4;

__device__ __forceinline__ short f2bf(float x){
  union { float f; uint32_t u; } v; v.f = x;
  uint32_t r = (v.u + 0x7FFFu + ((v.u >> 16) & 1u)) >> 16;
  return (short)(uint16_t)r;
}

__device__ __forceinline__ f32x4 mfma16(bf16x8 a, bf16x8 b, f32x4 c){
  return __builtin_amdgcn_mfma_f32_16x16x32_bf16(a, b, c, 0, 0, 0);
}

// ---------------- prep: pack weights into B-fragment layout (bf16) -------------
// wpk (shorts): [0,2048) embed (K=16 padded to 32, 1 kstep)
//   per layer l at 2048 + l*24576: +0 e1(K=128,8192) +8192 e2(K=64,4096)
//                                  +12288 n1(K=128,8192) +20480 n2(K=64,4096)
//   ro_w1 at 75776 (4096). total 79872 shorts.
// Fragment element (ks,nt,lane,e) holds W[ks*32 + (lane>>4)*8 + e][nt*16 + (lane&15)]
__global__ void prep_pack(const float* __restrict__ embed_w,
                          const float* __restrict__ ew1, const float* __restrict__ ew2,
                          const float* __restrict__ nw1, const float* __restrict__ nw2,
                          const float* __restrict__ row1,
                          short* __restrict__ wpk)
{
  int tid = blockIdx.x * 256 + threadIdx.x;
  if (tid >= 79872) return;
  const float* W; int Kact; int rem;
  if (tid < 2048){ W = embed_w; Kact = 16; rem = tid; }
  else if (tid < 75776){
    int t2 = tid - 2048; int layer = t2 / 24576; int r = t2 % 24576;
    if      (r < 8192)  { W = ew1 + layer*8192; Kact = 128; rem = r; }
    else if (r < 12288) { W = ew2 + layer*4096; Kact = 64;  rem = r - 8192; }
    else if (r < 20480) { W = nw1 + layer*8192; Kact = 128; rem = r - 12288; }
    else                { W = nw2 + layer*4096; Kact = 64;  rem = r - 20480; }
  } else { W = row1; Kact = 64; rem = tid - 75776; }
  int e = rem & 7, lane = (rem >> 3) & 63, nt = (rem >> 9) & 3, ks = rem >> 11;
  int k = ks*32 + (lane >> 4)*8 + e;
  int col = nt*16 + (lane & 15);
  float v = (k < Kact) ? W[k*64 + col] : 0.f;
  wpk[tid] = f2bf(v);
}

// pack ro_w2 with the output channel-permutation folded in, plus permuted bias.
// w2p layout: [nt(619)][ks(2)][lane(64)][e(8)]; p = nt*16 + (lane&15) is the
// OUTPUT-linear index (c*900 + y*30 + x); source column j = (y*30+x)*11 + c.
__global__ void prep_w2(const float* __restrict__ ro_w2, const float* __restrict__ ro_b2,
                        short* __restrict__ w2p, float* __restrict__ b2p)
{
  int tid = blockIdx.x * 256 + threadIdx.x;
  if (tid < 633856){
    int e = tid & 7, lane = (tid >> 3) & 63, ks = (tid >> 9) & 1, nt = tid >> 10;
    int k = ks*32 + (lane >> 4)*8 + e;
    int p = nt*16 + (lane & 15);
    float v = 0.f;
    if (p < 9900){ int c = p / 900, rm = p % 900; v = ro_w2[k*9900 + rm*11 + c]; }
    w2p[tid] = f2bf(v);
  } else if (tid < 633856 + 9904){
    int p = tid - 633856;
    float v = 0.f;
    if (p < 9900){ int c = p / 900, rm = p % 900; v = ro_b2[rm*11 + c]; }
    b2p[p] = v;
  }
}

// ---------------- phase A: embed + 3 GNN layers; one wave == one batch ---------
__global__ __launch_bounds__(256) void gnn_phaseA(
    const float* __restrict__ nf, const int* __restrict__ nn,
    const float* __restrict__ embb,
    const float* __restrict__ eb1, const float* __restrict__ eb2,
    const float* __restrict__ nb1, const float* __restrict__ nb2,
    const float* __restrict__ lng, const float* __restrict__ lnb,
    const short* __restrict__ wpk,
    float* __restrict__ gv)
{
  __shared__ short lds[4][6208];   // per wave: h 2048 | bufA 2048 | bufB 2048 | mm 64
  const int wave = threadIdx.x >> 6, lane = threadIdx.x & 63;
  const int l15 = lane & 15, lg = lane >> 4;
  const int b = blockIdx.x * 4 + wave;
  short* hs   = &lds[wave][0];
  short* bufA = &lds[wave][2048];
  short* bufB = &lds[wave][4096];
  short* mms  = &lds[wave][6144];
  const int n = nn[b];
  const float cinv = 1.0f / (float)(n < 1 ? 1 : n);

  float hD[2][4][4];     // residual stream in fp32 D-layout
  f32x4 acc[2][4];
  float colsum[4];

  // ---- embed: h0 = mask(nf @ embed_w + b) ----
  {
    bf16x8 aq[2];
    #pragma unroll
    for (int mt = 0; mt < 2; ++mt){
      int row = mt*16 + l15;
      bf16x8 a = (bf16x8)(short)0;
      if (row < 20 && lg < 2){
        const float* s = nf + (b*20 + row)*16 + lg*8;
        #pragma unroll
        for (int e = 0; e < 8; ++e) a[e] = f2bf(s[e]);
      }
      aq[mt] = a;
    }
    #pragma unroll
    for (int mt = 0; mt < 2; ++mt)
      #pragma unroll
      for (int nt = 0; nt < 4; ++nt){
        f32x4 z = {0.f, 0.f, 0.f, 0.f};
        bf16x8 bq = *(const bf16x8*)(wpk + (nt*64 + lane)*8);
        acc[mt][nt] = mfma16(aq[mt], bq, z);
      }
    #pragma unroll
    for (int nt = 0; nt < 4; ++nt) colsum[nt] = 0.f;
    #pragma unroll
    for (int nt = 0; nt < 4; ++nt){
      float bias = embb[nt*16 + l15];
      #pragma unroll
      for (int mt = 0; mt < 2; ++mt)
        #pragma unroll
        for (int e = 0; e < 4; ++e){
          int row = mt*16 + lg*4 + e;
          float v = acc[mt][nt][e] + bias;
          v = (row < n) ? v : 0.f;
          hD[mt][nt][e] = v;
          colsum[nt] += v;
          hs[((row*64) + (nt*16 + l15)) ^ ((row & 7) << 3)] = f2bf(v);
        }
    }
    #pragma unroll
    for (int nt = 0; nt < 4; ++nt){
      float s = colsum[nt];
      s += __shfl_xor(s, 16);
      s += __shfl_xor(s, 32);
      colsum[nt] = s * cinv;
    }
    float mv = (lg == 0) ? colsum[0] : (lg == 1) ? colsum[1] : (lg == 2) ? colsum[2] : colsum[3];
    mms[lane] = f2bf(mv);
  }

  // ---- 3 layers ----
  for (int li = 0; li < 3; ++li){
    const short* we1 = wpk + 2048 + li*24576;
    const short* we2 = we1 + 8192;
    const short* wn1 = we1 + 12288;
    const short* wn2 = we1 + 20480;

    // E1: [h, mm] @ We1  (K=128)
    #pragma unroll
    for (int mt = 0; mt < 2; ++mt)
      #pragma unroll
      for (int nt = 0; nt < 4; ++nt) acc[mt][nt] = (f32x4){0.f,0.f,0.f,0.f};
    #pragma unroll
    for (int ks = 0; ks < 4; ++ks){
      bf16x8 aq[2];
      if (ks < 2){
        #pragma unroll
        for (int mt = 0; mt < 2; ++mt){
          int row = mt*16 + l15;
          aq[mt] = *(const bf16x8*)&hs[((row*64) + (ks*32 + lg*8)) ^ ((row & 7) << 3)];
        }
      } else {
        bf16x8 m8 = *(const bf16x8*)&mms[(ks - 2)*32 + lg*8];
        aq[0] = m8; aq[1] = m8;
      }
      #pragma unroll
      for (int nt = 0; nt < 4; ++nt){
        bf16x8 bq = *(const bf16x8*)(we1 + ((ks*4 + nt)*64 + lane)*8);
        acc[0][nt] = mfma16(aq[0], bq, acc[0][nt]);
        acc[1][nt] = mfma16(aq[1], bq, acc[1][nt]);
      }
    }
    #pragma unroll
    for (int nt = 0; nt < 4; ++nt){
      float bias = eb1[li*64 + nt*16 + l15];
      #pragma unroll
      for (int mt = 0; mt < 2; ++mt)
        #pragma unroll
        for (int e = 0; e < 4; ++e){
          int row = mt*16 + lg*4 + e;
          float v = acc[mt][nt][e] + bias;
          v = v > 0.f ? v : 0.f;
          bufA[((row*64) + (nt*16 + l15)) ^ ((row & 7) << 3)] = f2bf(v);
        }
    }

    // E2: bufA @ We2 + eb2 -> bufB  (K=64)
    #pragma unroll
    for (int mt = 0; mt < 2; ++mt)
      #pragma unroll
      for (int nt = 0; nt < 4; ++nt) acc[mt][nt] = (f32x4){0.f,0.f,0.f,0.f};
    #pragma unroll
    for (int ks = 0; ks < 2; ++ks){
      bf16x8 aq[2];
      #pragma unroll
      for (int mt = 0; mt < 2; ++mt){
        int row = mt*16 + l15;
        aq[mt] = *(const bf16x8*)&bufA[((row*64) + (ks*32 + lg*8)) ^ ((row & 7) << 3)];
      }
      #pragma unroll
      for (int nt = 0; nt < 4; ++nt){
        bf16x8 bq = *(const bf16x8*)(we2 + ((ks*4 + nt)*64 + lane)*8);
        acc[0][nt] = mfma16(aq[0], bq, acc[0][nt]);
        acc[1][nt] = mfma16(aq[1], bq, acc[1][nt]);
      }
    }
    #pragma unroll
    for (int nt = 0; nt < 4; ++nt){
      float bias = eb2[li*64 + nt*16 + l15];
      #pragma unroll
      for (int mt = 0; mt < 2; ++mt)
        #pragma unroll
        for (int e = 0; e < 4; ++e){
          int row = mt*16 + lg*4 + e;
          bufB[((row*64) + (nt*16 + l15)) ^ ((row & 7) << 3)] = f2bf(acc[mt][nt][e] + bias);
        }
    }

    // N1: [h, edge_msg] @ Wn1, relu -> bufA  (K=128)
    #pragma unroll
    for (int mt = 0; mt < 2; ++mt)
      #pragma unroll
      for (int nt = 0; nt < 4; ++nt) acc[mt][nt] = (f32x4){0.f,0.f,0.f,0.f};
    #pragma unroll
    for (int ks = 0; ks < 4; ++ks){
      bf16x8 aq[2];
      #pragma unroll
      for (int mt = 0; mt < 2; ++mt){
        int row = mt*16 + l15;
        const short* src = (ks < 2) ? hs : bufB;
        int k0 = (ks < 2) ? (ks*32 + lg*8) : ((ks - 2)*32 + lg*8);
        aq[mt] = *(const bf16x8*)&src[((row*64) + k0) ^ ((row & 7) << 3)];
      }
      #pragma unroll
      for (int nt = 0; nt < 4; ++nt){
        bf16x8 bq = *(const bf16x8*)(wn1 + ((ks*4 + nt)*64 + lane)*8);
        acc[0][nt] = mfma16(aq[0], bq, acc[0][nt]);
        acc[1][nt] = mfma16(aq[1], bq, acc[1][nt]);
      }
    }
    #pragma unroll
    for (int nt = 0; nt < 4; ++nt){
      float bias = nb1[li*64 + nt*16 + l15];
      #pragma unroll
      for (int mt = 0; mt < 2; ++mt)
        #pragma unroll
        for (int e = 0; e < 4; ++e){
          int row = mt*16 + lg*4 + e;
          float v = acc[mt][nt][e] + bias;
          v = v > 0.f ? v : 0.f;
          bufA[((row*64) + (nt*16 + l15)) ^ ((row & 7) << 3)] = f2bf(v);
        }
    }

    // N2: bufA @ Wn2 + nb2; h = mask(LN(h + .)) -> hs, hD, mm/gv  (K=64)
    #pragma unroll
    for (int mt = 0; mt < 2; ++mt)
      #pragma unroll
      for (int nt = 0; nt < 4; ++nt) acc[mt][nt] = (f32x4){0.f,0.f,0.f,0.f};
    #pragma unroll
    for (int ks = 0; ks < 2; ++ks){
      bf16x8 aq[2];
      #pragma unroll
      for (int mt = 0; mt < 2; ++mt){
        int row = mt*16 + l15;
        aq[mt] = *(const bf16x8*)&bufA[((row*64) + (ks*32 + lg*8)) ^ ((row & 7) << 3)];
      }
      #pragma unroll
      for (int nt = 0; nt < 4; ++nt){
        bf16x8 bq = *(const bf16x8*)(wn2 + ((ks*4 + nt)*64 + lane)*8);
        acc[0][nt] = mfma16(aq[0], bq, acc[0][nt]);
        acc[1][nt] = mfma16(aq[1], bq, acc[1][nt]);
      }
    }
    float g4[4], b4[4];
    #pragma unroll
    for (int nt = 0; nt < 4; ++nt){
      float bias = nb2[li*64 + nt*16 + l15];
      g4[nt] = lng[li*64 + nt*16 + l15];
      b4[nt] = lnb[li*64 + nt*16 + l15];
      #pragma unroll
      for (int mt = 0; mt < 2; ++mt)
        #pragma unroll
        for (int e = 0; e < 4; ++e)
          hD[mt][nt][e] += acc[mt][nt][e] + bias;
      colsum[nt] = 0.f;
    }
    #pragma unroll
    for (int mt = 0; mt < 2; ++mt)
      #pragma unroll
      for (int e = 0; e < 4; ++e){
        float s1 = 0.f, s2 = 0.f;
        #pragma unroll
        for (int nt = 0; nt < 4; ++nt){ float v = hD[mt][nt][e]; s1 += v; s2 += v*v; }
        #pragma unroll
        for (int m = 1; m < 16; m <<= 1){ s1 += __shfl_xor(s1, m); s2 += __shfl_xor(s2, m); }
        float mean = s1 * 0.015625f;
        float var  = s2 * 0.015625f - mean*mean;
        float rstd = rsqrtf(var + 1e-5f);
        int row = mt*16 + lg*4 + e;
        bool keep = row < n;
        #pragma unroll
        for (int nt = 0; nt < 4; ++nt){
          float y = (hD[mt][nt][e] - mean) * rstd * g4[nt] + b4[nt];
          y = keep ? y : 0.f;
          hD[mt][nt][e] = y;
          colsum[nt] += y;
          hs[((row*64) + (nt*16 + l15)) ^ ((row & 7) << 3)] = f2bf(y);
        }
      }
    #pragma unroll
    for (int nt = 0; nt < 4; ++nt){
      float s = colsum[nt];
      s += __shfl_xor(s, 16);
      s += __shfl_xor(s, 32);
      colsum[nt] = s * cinv;
    }
    float mv = (lg == 0) ? colsum[0] : (lg == 1) ? colsum[1] : (lg == 2) ? colsum[2] : colsum[3];
    if (li < 2) mms[lane] = f2bf(mv);
    else        gv[b*64 + lane] = mv;   // graph_vec (mask already applied)
  }
}

// ---------------- phase B: out = relu(gv@ro_w1+b1) @ w2p + b2p (store-bound) ---
__global__ __launch_bounds__(256) void gnn_phaseB(
    const float* __restrict__ gv, const float* __restrict__ rb1,
    const short* __restrict__ wro1, const short* __restrict__ w2p,
    const float* __restrict__ b2p, float* __restrict__ out)
{
  __shared__ short tl[4][1024];
  const int wave = threadIdx.x >> 6, lane = threadIdx.x & 63;
  const int l15 = lane & 15, lg = lane >> 4;
  const int b0 = blockIdx.x * 64 + wave * 16;

  // t = relu(gv @ ro_w1 + b1) for this wave's 16 rows
  f32x4 tacc[4];
  #pragma unroll
  for (int nt = 0; nt < 4; ++nt) tacc[nt] = (f32x4){0.f,0.f,0.f,0.f};
  #pragma unroll
  for (int ks = 0; ks < 2; ++ks){
    bf16x8 a;
    const float* s = gv + (b0 + l15)*64 + ks*32 + lg*8;
    #pragma unroll
    for (int e = 0; e < 8; ++e) a[e] = f2bf(s[e]);
    #pragma unroll
    for (int nt = 0; nt < 4; ++nt){
      bf16x8 bq = *(const bf16x8*)(wro1 + ((ks*4 + nt)*64 + lane)*8);
      tacc[nt] = mfma16(a, bq, tacc[nt]);
    }
  }
  short* tw = tl[wave];
  #pragma unroll
  for (int nt = 0; nt < 4; ++nt){
    float bias = rb1[nt*16 + l15];
    #pragma unroll
    for (int e = 0; e < 4; ++e){
      int row = lg*4 + e;
      float v = tacc[nt][e] + bias;
      v = v > 0.f ? v : 0.f;
      tw[((row*64) + (nt*16 + l15)) ^ ((row & 7) << 3)] = f2bf(v);
    }
  }
  bf16x8 ta0 = *(const bf16x8*)&tw[((l15*64) + (lg*8))      ^ ((l15 & 7) << 3)];
  bf16x8 ta1 = *(const bf16x8*)&tw[((l15*64) + (32 + lg*8)) ^ ((l15 & 7) << 3)];

  const int nt0 = blockIdx.y * 124;
  const int nt1 = (nt0 + 124 < 619) ? nt0 + 124 : 619;
  for (int nt = nt0; nt < nt1; ++nt){
    const bf16x8* wp = (const bf16x8*)w2p + nt*128;
    f32x4 c = (f32x4){0.f,0.f,0.f,0.f};
    c = mfma16(ta0, wp[lane], c);
    c = mfma16(ta1, wp[64 + lane], c);
    int p = nt*16 + l15;
    if (p < 9900){
      float bias = b2p[p];
      float* o = out + (b0 + lg*4)*9900 + p;
      #pragma unroll
      for (int e = 0; e < 4; ++e) o[e*9900] = c[e] + bias;
    }
  }
}

extern "C" void kernel_launch(void* const* d_in, const int* in_sizes, int n_in,
                              void* d_out, int out_size, void* d_ws, size_t ws_size,
                              hipStream_t stream)
{
  const float* nf   = (const float*)d_in[0];
  const int*   nn   = (const int*)d_in[1];
  const float* embw = (const float*)d_in[2];
  const float* embb = (const float*)d_in[3];
  const float* ew1  = (const float*)d_in[4];
  const float* eb1  = (const float*)d_in[5];
  const float* ew2  = (const float*)d_in[6];
  const float* eb2  = (const float*)d_in[7];
  const float* nw1  = (const float*)d_in[8];
  const float* nb1  = (const float*)d_in[9];
  const float* nw2  = (const float*)d_in[10];
  const float* nb2  = (const float*)d_in[11];
  const float* lng  = (const float*)d_in[12];
  const float* lnb  = (const float*)d_in[13];
  const float* rw1  = (const float*)d_in[14];
  const float* rb1  = (const float*)d_in[15];
  const float* rw2  = (const float*)d_in[16];
  const float* rb2  = (const float*)d_in[17];
  float* out = (float*)d_out;

  const int B = in_sizes[0] / 320;   // 16384

  char* ws = (char*)d_ws;
  float* gv  = (float*)ws;                                   // B*64 f32
  float* b2p = (float*)(ws + (size_t)B*64*4);                // 9904 f32
  short* wpk = (short*)(ws + (size_t)B*64*4 + 9904*4);       // 79872 shorts
  short* w2p = wpk + 79872;                                  // 633856 shorts

  prep_pack<<<(79872 + 255)/256, 256, 0, stream>>>(embw, ew1, ew2, nw1, nw2, rw1, wpk);
  prep_w2<<<(633856 + 9904 + 255)/256, 256, 0, stream>>>(rw2, rb2, w2p, b2p);
  gnn_phaseA<<<B/4, 256, 0, stream>>>(nf, nn, embb, eb1, eb2, nb1, nb2, lng, lnb, wpk, gv);
  gnn_phaseB<<<dim3(B/64, 5), 256, 0, stream>>>(gv, rb1, wpk + 75776, w2p, b2p, out);
}